// Round 13
// baseline (131.396 us; speedup 1.0000x reference)
//
#include <hip/hip_runtime.h>
#include <hip/hip_cooperative_groups.h>
#include <math.h>

namespace cg = cooperative_groups;

// ---------------------------------------------------------------------------
// N-pair Gaussian mixture log-likelihood, factorized form:
//   arg_ij(x) = g_i(x) + g_j(x) + c_ij,  g_i(x) = -0.5 x'prec_i x + x'rhs_i
//   pdf(x)    = u' E u,  u_i = exp(g_i(x)),  E_ij = exp(c_ij + 64 ln2)  [scaled]
//   out       = mean_n( log pdf_n ) + log z_last   (scale folded into Kconst)
// ONE cooperative dispatch: block 0 setup -> grid.sync -> all blocks main
// (R9-proven 4pt/thread pk_fma body) -> grid.sync -> block 0 final reduce.
// No atomics, fixed-order sums -> deterministic.
// ---------------------------------------------------------------------------

#define LOG2E_F 1.4426950408889634f
#define LN2_F   0.6931471805599453f
#define LN2PI_F 1.8378770664093453f   // ln(2*pi)

// ws layout (float offsets). Staged region = [0,1024) = 256 float4.
#define WS_COEF 0      // 16 rows * 48: per d {lin_d, Q_dd..Q_d7} *log2e; 44 used
#define WS_ES   768    // 160: packed lower-tri E rows, each padded to 16B
#define WS_K    1024   // Kconst = log z_last - 64 ln2  (outside staged region)
#define WS_PART 1088   // per-block partial sums

typedef float f2 __attribute__((ext_vector_type(2)));

__device__ const int EOFF_D[16] = {0,4,8,12,16,24,32,40,48,60,72,84,96,112,128,144};

__device__ __forceinline__ float fexp2(float x) {
#if __has_builtin(__builtin_amdgcn_exp2f)
  return __builtin_amdgcn_exp2f(x);
#else
  return exp2f(x);
#endif
}
__device__ __forceinline__ float flog2(float x) {
#if __has_builtin(__builtin_amdgcn_logf)
  return __builtin_amdgcn_logf(x);
#else
  return log2f(x);
#endif
}
__device__ __forceinline__ f2 vfma(float c, f2 x, f2 a) {   // v_pk_fma_f32
  return __builtin_elementwise_fma((f2){c, c}, x, a);
}

// Cholesky: A = C C^T (lower). Only lower triangle of A read. Fully unrolled.
__device__ __forceinline__ void chol8(const float (*A)[8], float (*C)[8]) {
  #pragma unroll
  for (int d = 0; d < 8; ++d) {
    float s = A[d][d];
    #pragma unroll
    for (int m = 0; m < 8; ++m) if (m < d) s -= C[d][m] * C[d][m];
    float cd = sqrtf(s);
    C[d][d] = cd;
    float inv = 1.f / cd;
    #pragma unroll
    for (int e = 0; e < 8; ++e) if (e > d) {
      float t = A[e][d];
      #pragma unroll
      for (int m = 0; m < 8; ++m) if (m < d) t -= C[e][m] * C[d][m];
      C[e][d] = t * inv;
    }
  }
}

__global__ __launch_bounds__(256, 2) void gm_coop(const float* __restrict__ X,
                                                  const float* __restrict__ mu,
                                                  const float* __restrict__ L,
                                                  const float* __restrict__ wts,
                                                  float* ws, float* out,
                                                  int N, int nb, float invN) {
  cg::grid_group grid = cg::this_grid();
  __shared__ float sp[16][72];   // setup scratch (block 0 only)
  __shared__ float sc[1024];     // [0,768) coef rows; [768,928) padded E; pad
  const int tid = threadIdx.x;

  // --- all blocks: issue X loads first (independent of ws; hides latency) --
  const int base = blockIdx.x * 1024 + tid;
  bool act[4];
  float4 xa[4], xb[4];
  #pragma unroll
  for (int g = 0; g < 4; ++g) {
    int gid = base + g * 256;
    act[g] = gid < N;
    const float4* Xv =
        reinterpret_cast<const float4*>(X) + (size_t)(act[g] ? gid : 0) * 2;
    xa[g] = Xv[0];
    xb[g] = Xv[1];
  }

  // --- phase 1: block 0 computes all constants into ws ---------------------
  if (blockIdx.x == 0) {
    ws[768 + tid] = 0.f;         // zero [768,1024): E pads + tail
    if (tid < 16) {
      int k = tid;
      float Lt[8][8];
      #pragma unroll
      for (int d = 0; d < 8; ++d)
        #pragma unroll
        for (int e = 0; e < 8; ++e)
          Lt[d][e] = (e <= d) ? L[k * 64 + d * 8 + e] : 0.f;
      float A[8][8];
      #pragma unroll
      for (int d = 0; d < 8; ++d)
        #pragma unroll
        for (int e = 0; e <= d; ++e) {
          float s = (d == e) ? 1.f : 0.f;
          #pragma unroll
          for (int m = 0; m < 8; ++m) s += Lt[d][m] * Lt[e][m];
          A[d][e] = s;
          A[e][d] = s;
        }
      float C[8][8];
      chol8(A, C);
      float Ci[8][8];
      #pragma unroll
      for (int d = 0; d < 8; ++d) Ci[d][d] = 1.f / C[d][d];
      #pragma unroll
      for (int e = 0; e < 8; ++e)
        #pragma unroll
        for (int d = 0; d < 8; ++d) if (d > e) {
          float s = 0.f;
          #pragma unroll
          for (int m = 0; m < 8; ++m) if (m >= e && m < d) s += C[d][m] * Ci[m][e];
          Ci[d][e] = -s * Ci[d][d];
        }
      #pragma unroll
      for (int a = 0; a < 8; ++a)
        #pragma unroll
        for (int b = 0; b < 8; ++b) {
          float s = 0.f;
          #pragma unroll
          for (int m = 0; m < 8; ++m) if (m >= a && m >= b) s += Ci[m][a] * Ci[m][b];
          sp[k][a * 8 + b] = s;
        }
      #pragma unroll
      for (int d = 0; d < 8; ++d) {
        float s = 0.f;
        #pragma unroll
        for (int e = 0; e < 8; ++e) s += sp[k][d * 8 + e] * mu[k * 8 + e];
        sp[k][64 + d] = s;
      }
    }
    __syncthreads();

    const int p = tid;
    const int i = p >> 4, j = p & 15;
    const float* pi = sp[i];
    const float* pj = sp[j];
    float P[8][8], rp[8];
    #pragma unroll
    for (int d = 0; d < 8; ++d) {
      #pragma unroll
      for (int e = 0; e < 8; ++e) P[d][e] = pi[d * 8 + e] + pj[d * 8 + e];
      rp[d] = pi[64 + d] + pj[64 + d];
    }
    float U[8][8];
    chol8(P, U);
    float logdet = 0.f;
    #pragma unroll
    for (int d = 0; d < 8; ++d) logdet += logf(U[d][d]);
    logdet *= 2.f;
    float zf[8];
    #pragma unroll
    for (int d = 0; d < 8; ++d) {
      float s = rp[d];
      #pragma unroll
      for (int m = 0; m < 8; ++m) if (m < d) s -= U[d][m] * zf[m];
      zf[d] = s / U[d][d];
    }
    float y[8];
    #pragma unroll
    for (int dd = 7; dd >= 0; --dd) {
      float s = zf[dd];
      #pragma unroll
      for (int m = 0; m < 8; ++m) if (m > dd) s -= U[m][dd] * y[m];
      y[dd] = s / U[dd][dd];
    }
    float muPmu = 0.f;
    #pragma unroll
    for (int d = 0; d < 8; ++d) muPmu += rp[d] * y[d];
    float c = -0.5f * muPmu + 0.5f * logdet - 32.f * LN2PI_F
            + logf(wts[i]) + logf(wts[j]) + 64.f * LN2_F;
    float Ev = expf(c);
    if (j <= i)   // padded-packed lower triangle; factor 2 folded off-diag
      ws[WS_ES + EOFF_D[i] + j] = (i == j) ? Ev : 2.f * Ev;
    if (i == j) { // coefficient row, interleaved {lin_d, Q_dd..Q_d7} * log2e
      float* c0 = ws + WS_COEF + i * 48;
      int q = 0;
      #pragma unroll
      for (int d = 0; d < 8; ++d) {
        c0[q++] = pi[64 + d] * LOG2E_F;               // lin_d
        #pragma unroll
        for (int e = d; e < 8; ++e) {
          float v = (d == e) ? -0.5f * pi[d * 8 + e] : -pi[d * 8 + e];
          c0[q++] = v * LOG2E_F;                      // Q_de
        }
      }
      c0[44] = 0.f; c0[45] = 0.f; c0[46] = 0.f; c0[47] = 0.f;
    }
    if (p == 255) ws[WS_K] = 0.5f * logdet - 32.f * LN2PI_F - 64.f * LN2_F;
  }

  grid.sync();   // constants visible grid-wide

  // --- phase 2: stage constants to LDS; compute 4 pts/thread ---------------
  reinterpret_cast<float4*>(sc)[tid] =
      reinterpret_cast<const float4*>(ws)[tid];
  __syncthreads();

  f2 xs01[8], xs23[8];
  xs01[0] = (f2){xa[0].x, xa[1].x}; xs23[0] = (f2){xa[2].x, xa[3].x};
  xs01[1] = (f2){xa[0].y, xa[1].y}; xs23[1] = (f2){xa[2].y, xa[3].y};
  xs01[2] = (f2){xa[0].z, xa[1].z}; xs23[2] = (f2){xa[2].z, xa[3].z};
  xs01[3] = (f2){xa[0].w, xa[1].w}; xs23[3] = (f2){xa[2].w, xa[3].w};
  xs01[4] = (f2){xb[0].x, xb[1].x}; xs23[4] = (f2){xb[2].x, xb[3].x};
  xs01[5] = (f2){xb[0].y, xb[1].y}; xs23[5] = (f2){xb[2].y, xb[3].y};
  xs01[6] = (f2){xb[0].z, xb[1].z}; xs23[6] = (f2){xb[2].z, xb[3].z};
  xs01[7] = (f2){xb[0].w, xb[1].w}; xs23[7] = (f2){xb[2].w, xb[3].w};

  constexpr int D_OF[44] = {0,0,0,0,0,0,0,0,0,
                            1,1,1,1,1,1,1,1,
                            2,2,2,2,2,2,2,
                            3,3,3,3,3,3,
                            4,4,4,4,4,
                            5,5,5,5,
                            6,6,6,
                            7,7};
  constexpr int E_OF[44] = {-1,0,1,2,3,4,5,6,7,
                            -1,1,2,3,4,5,6,7,
                            -1,2,3,4,5,6,7,
                            -1,3,4,5,6,7,
                            -1,4,5,6,7,
                            -1,5,6,7,
                            -1,6,7,
                            -1,7};

  f2 u01[16], u23[16];
  #pragma unroll
  for (int i = 0; i < 16; ++i) {
    const float4* c4 = reinterpret_cast<const float4*>(sc + i * 48);
    f2 g01 = (f2){0.f, 0.f}, g23 = (f2){0.f, 0.f};
    f2 r01 = (f2){0.f, 0.f}, r23 = (f2){0.f, 0.f};
    #pragma unroll
    for (int v = 0; v < 11; ++v) {            // 11x ds_read_b128 broadcast
      float4 w = c4[v];
      #pragma unroll
      for (int k2 = 0; k2 < 4; ++k2) {
        const int q = 4 * v + k2;
        const float cc = (k2 == 0) ? w.x : (k2 == 1) ? w.y : (k2 == 2) ? w.z : w.w;
        if (E_OF[q] < 0) {                    // start of row d: flush prev row
          if (q > 0) {
            g01 = __builtin_elementwise_fma(xs01[D_OF[q - 1]], r01, g01);
            g23 = __builtin_elementwise_fma(xs23[D_OF[q - 1]], r23, g23);
          }
          r01 = (f2){cc, cc};
          r23 = (f2){cc, cc};
        } else {
          r01 = vfma(cc, xs01[E_OF[q]], r01);
          r23 = vfma(cc, xs23[E_OF[q]], r23);
        }
      }
    }
    g01 = __builtin_elementwise_fma(xs01[7], r01, g01);  // flush row 7
    g23 = __builtin_elementwise_fma(xs23[7], r23, g23);
    u01[i] = (f2){fexp2(g01.x), fexp2(g01.y)};
    u23[i] = (f2){fexp2(g23.x), fexp2(g23.y)};
  }

  constexpr int EOFF[16]  = {0,4,8,12,16,24,32,40,48,60,72,84,96,112,128,144};
  constexpr int ELEN4[16] = {1,1,1,1,2,2,2,2,3,3,3,3,4,4,4,4};
  const float4* es4 = reinterpret_cast<const float4*>(sc + 768);
  f2 pdf01 = (f2){0.f, 0.f}, pdf23 = (f2){0.f, 0.f};
  #pragma unroll
  for (int i = 0; i < 16; ++i) {
    f2 s01 = (f2){0.f, 0.f}, s23 = (f2){0.f, 0.f};
    #pragma unroll
    for (int q4 = 0; q4 < ELEN4[i]; ++q4) {   // ds_read_b128 per 4 E entries
      float4 ev = es4[EOFF[i] / 4 + q4];
      const int j = q4 * 4;
      s01 = vfma(ev.x, u01[j + 0], s01); s23 = vfma(ev.x, u23[j + 0], s23);
      s01 = vfma(ev.y, u01[j + 1], s01); s23 = vfma(ev.y, u23[j + 1], s23);
      s01 = vfma(ev.z, u01[j + 2], s01); s23 = vfma(ev.z, u23[j + 2], s23);
      s01 = vfma(ev.w, u01[j + 3], s01); s23 = vfma(ev.w, u23[j + 3], s23);
    }
    pdf01 = __builtin_elementwise_fma(u01[i], s01, pdf01);
    pdf23 = __builtin_elementwise_fma(u23[i], s23, pdf23);
  }
  float lsum = 0.f;
  if (act[0]) lsum += flog2(pdf01.x);
  if (act[1]) lsum += flog2(pdf01.y);
  if (act[2]) lsum += flog2(pdf23.x);
  if (act[3]) lsum += flog2(pdf23.y);

  // deterministic block reduction of sum(log2 pdf)
  #pragma unroll
  for (int off = 32; off > 0; off >>= 1) lsum += __shfl_down(lsum, off, 64);
  __shared__ float wsum[4];
  int lane = threadIdx.x & 63, wid = threadIdx.x >> 6;
  if (lane == 0) wsum[wid] = lsum;
  __syncthreads();
  if (tid == 0)
    ws[WS_PART + blockIdx.x] = (wsum[0] + wsum[1]) + (wsum[2] + wsum[3]);

  grid.sync();   // all partials visible

  // --- phase 3: block 0 final reduce (fixed order -> deterministic) --------
  if (blockIdx.x == 0) {
    const float* partials = ws + WS_PART;
    float s = 0.f;
    for (int q = tid; q < nb; q += 256) s += partials[q];
    #pragma unroll
    for (int off = 32; off > 0; off >>= 1) s += __shfl_down(s, off, 64);
    if (lane == 0) wsum[wid] = s;
    __syncthreads();
    if (tid == 0) {
      float tot = (wsum[0] + wsum[1]) + (wsum[2] + wsum[3]);
      // mean(ln pdf_true) + ln z_last = ln2 * mean(log2 pdf_scaled) + Kconst
      out[0] = tot * LN2_F * invN + ws[WS_K];
    }
  }
}

extern "C" void kernel_launch(void* const* d_in, const int* in_sizes, int n_in,
                              void* d_out, int out_size, void* d_ws, size_t ws_size,
                              hipStream_t stream) {
  const float* X = (const float*)d_in[0];
  const float* mu = (const float*)d_in[1];
  const float* L = (const float*)d_in[2];
  const float* wts = (const float*)d_in[3];
  // d_in[4] ("it") is unused by the reference math.
  float* ws = (float*)d_ws;
  float* out = (float*)d_out;
  int N = in_sizes[0] / 8;
  int nb = (N + 1023) / 1024;            // 4 points per thread, 256 threads
  float invN = 1.0f / (float)N;
  void* args[] = {(void*)&X, (void*)&mu, (void*)&L, (void*)&wts,
                  (void*)&ws, (void*)&out, (void*)&N, (void*)&nb, (void*)&invN};
  hipLaunchCooperativeKernel(reinterpret_cast<void*>(gm_coop), dim3(nb),
                             dim3(256), args, 0, stream);
}

// Round 14
// 24.924 us; speedup vs baseline: 5.2718x; 5.2718x over previous
//
#include <hip/hip_runtime.h>
#include <math.h>

// ---------------------------------------------------------------------------
// N-pair Gaussian mixture log-likelihood, factorized form:
//   arg_ij(x) = g_i(x) + g_j(x) + c_ij,  g_i(x) = -0.5 x'prec_i x + x'rhs_i
//   pdf(x)    = u' E u,  u_i = exp(g_i(x)),  E_ij = exp(c_ij + 64 ln2)  [scaled]
//   out       = mean_n( log pdf_n ) + log z_last   (scale folded into Kconst)
// Three kernels (proven best structure). Main: BLOCK=128, 4 pts/thread
// (977 blocks = 3.8 blocks/CU -> 2x the waves/SIMD of the 256-thread config
// at identical per-point LDS amortization) with the R9-proven pk_fma body.
// ---------------------------------------------------------------------------

#define LOG2E_F 1.4426950408889634f
#define LN2_F   0.6931471805599453f
#define LN2PI_F 1.8378770664093453f   // ln(2*pi)

// ws layout (float offsets). Staged region = [0,1024) = 256 float4.
#define WS_COEF 0      // 16 rows * 48: per d {lin_d, Q_dd..Q_d7} *log2e; 44 used
#define WS_ES   768    // 160: packed lower-tri E rows, each padded to 16B
#define WS_K    1024   // Kconst = log z_last - 64 ln2  (outside staged region)
#define WS_PART 1088   // per-block partial sums (nb <= ~2048)

typedef float f2 __attribute__((ext_vector_type(2)));

// Padded-packed E row offsets (floats)
__device__ const int EOFF_D[16] = {0,4,8,12,16,24,32,40,48,60,72,84,96,112,128,144};

__device__ __forceinline__ float fexp2(float x) {
#if __has_builtin(__builtin_amdgcn_exp2f)
  return __builtin_amdgcn_exp2f(x);
#else
  return exp2f(x);
#endif
}
__device__ __forceinline__ float flog2(float x) {
#if __has_builtin(__builtin_amdgcn_logf)
  return __builtin_amdgcn_logf(x);
#else
  return log2f(x);
#endif
}
__device__ __forceinline__ f2 vfma(float c, f2 x, f2 a) {   // v_pk_fma_f32
  return __builtin_elementwise_fma((f2){c, c}, x, a);
}

// Cholesky: A = C C^T (lower). Only lower triangle of A read. Fully unrolled.
__device__ __forceinline__ void chol8(const float (*A)[8], float (*C)[8]) {
  #pragma unroll
  for (int d = 0; d < 8; ++d) {
    float s = A[d][d];
    #pragma unroll
    for (int m = 0; m < 8; ++m) if (m < d) s -= C[d][m] * C[d][m];
    float cd = sqrtf(s);
    C[d][d] = cd;
    float inv = 1.f / cd;
    #pragma unroll
    for (int e = 0; e < 8; ++e) if (e > d) {
      float t = A[e][d];
      #pragma unroll
      for (int m = 0; m < 8; ++m) if (m < d) t -= C[e][m] * C[d][m];
      C[e][d] = t * inv;
    }
  }
}

// ---------------------------------------------------------------------------
// Kernel A: all setup in one block (unchanged; correctness-proven).
// ---------------------------------------------------------------------------
__global__ __launch_bounds__(256) void gm_setup(const float* __restrict__ mu,
                                                const float* __restrict__ L,
                                                const float* __restrict__ wts,
                                                float* __restrict__ ws) {
  __shared__ float sp[16][72];   // prec[64] + rhs[8] per component
  int tid = threadIdx.x;
  ws[768 + tid] = 0.f;           // zero [768,1024): E pads + tail
  if (tid < 16) {
    int k = tid;
    float Lt[8][8];
    #pragma unroll
    for (int d = 0; d < 8; ++d)
      #pragma unroll
      for (int e = 0; e < 8; ++e)
        Lt[d][e] = (e <= d) ? L[k * 64 + d * 8 + e] : 0.f;
    float A[8][8];
    #pragma unroll
    for (int d = 0; d < 8; ++d)
      #pragma unroll
      for (int e = 0; e <= d; ++e) {
        float s = (d == e) ? 1.f : 0.f;
        #pragma unroll
        for (int m = 0; m < 8; ++m) s += Lt[d][m] * Lt[e][m];
        A[d][e] = s;
        A[e][d] = s;
      }
    float C[8][8];
    chol8(A, C);
    float Ci[8][8];
    #pragma unroll
    for (int d = 0; d < 8; ++d) Ci[d][d] = 1.f / C[d][d];
    #pragma unroll
    for (int e = 0; e < 8; ++e)
      #pragma unroll
      for (int d = 0; d < 8; ++d) if (d > e) {
        float s = 0.f;
        #pragma unroll
        for (int m = 0; m < 8; ++m) if (m >= e && m < d) s += C[d][m] * Ci[m][e];
        Ci[d][e] = -s * Ci[d][d];
      }
    #pragma unroll
    for (int a = 0; a < 8; ++a)
      #pragma unroll
      for (int b = 0; b < 8; ++b) {
        float s = 0.f;
        #pragma unroll
        for (int m = 0; m < 8; ++m) if (m >= a && m >= b) s += Ci[m][a] * Ci[m][b];
        sp[k][a * 8 + b] = s;
      }
    #pragma unroll
    for (int d = 0; d < 8; ++d) {
      float s = 0.f;
      #pragma unroll
      for (int e = 0; e < 8; ++e) s += sp[k][d * 8 + e] * mu[k * 8 + e];
      sp[k][64 + d] = s;
    }
  }
  __syncthreads();

  int p = tid;
  int i = p >> 4, j = p & 15;
  const float* pi = sp[i];
  const float* pj = sp[j];
  float P[8][8], rp[8];
  #pragma unroll
  for (int d = 0; d < 8; ++d) {
    #pragma unroll
    for (int e = 0; e < 8; ++e) P[d][e] = pi[d * 8 + e] + pj[d * 8 + e];
    rp[d] = pi[64 + d] + pj[64 + d];
  }
  float U[8][8];
  chol8(P, U);
  float logdet = 0.f;
  #pragma unroll
  for (int d = 0; d < 8; ++d) logdet += logf(U[d][d]);
  logdet *= 2.f;
  float zf[8];
  #pragma unroll
  for (int d = 0; d < 8; ++d) {
    float s = rp[d];
    #pragma unroll
    for (int m = 0; m < 8; ++m) if (m < d) s -= U[d][m] * zf[m];
    zf[d] = s / U[d][d];
  }
  float y[8];
  #pragma unroll
  for (int dd = 7; dd >= 0; --dd) {
    float s = zf[dd];
    #pragma unroll
    for (int m = 0; m < 8; ++m) if (m > dd) s -= U[m][dd] * y[m];
    y[dd] = s / U[dd][dd];
  }
  float muPmu = 0.f;
  #pragma unroll
  for (int d = 0; d < 8; ++d) muPmu += rp[d] * y[d];
  float c = -0.5f * muPmu + 0.5f * logdet - 32.f * LN2PI_F
          + logf(wts[i]) + logf(wts[j]) + 64.f * LN2_F;
  float Ev = expf(c);
  if (j <= i)   // padded-packed lower triangle; factor 2 folded off-diagonal
    ws[WS_ES + EOFF_D[i] + j] = (i == j) ? Ev : 2.f * Ev;
  if (i == j) { // main-loop coefficient row, interleaved {lin_d, Q_dd..Q_d7}
    float* c0 = ws + WS_COEF + i * 48;
    int q = 0;
    #pragma unroll
    for (int d = 0; d < 8; ++d) {
      c0[q++] = pi[64 + d] * LOG2E_F;                 // lin_d
      #pragma unroll
      for (int e = d; e < 8; ++e) {
        float v = (d == e) ? -0.5f * pi[d * 8 + e] : -pi[d * 8 + e];
        c0[q++] = v * LOG2E_F;                        // Q_de
      }
    }
    c0[44] = 0.f; c0[45] = 0.f; c0[46] = 0.f; c0[47] = 0.f;
  }
  if (p == 255) ws[WS_K] = 0.5f * logdet - 32.f * LN2PI_F - 64.f * LN2_F;
}

// ---------------------------------------------------------------------------
// Kernel B: main N-loop. BLOCK=128, 4 pts/thread as two f2 packs (pk_fma).
// 977 blocks = 3.8 blocks/CU = 2x waves/SIMD vs the 256-thread config, at
// identical per-point LDS-broadcast amortization (isolates TLP).
// ---------------------------------------------------------------------------
__global__ __launch_bounds__(128) void gm_main(const float* __restrict__ X,
                                               const float* __restrict__ cf,
                                               float* __restrict__ partials,
                                               int N) {
  __shared__ float sc[1024];   // [0,768) coef rows; [768,928) padded E; pad
  {
    const float4* cf4 = reinterpret_cast<const float4*>(cf);
    float4* s4 = reinterpret_cast<float4*>(sc);
    s4[threadIdx.x] = cf4[threadIdx.x];
    s4[threadIdx.x + 128] = cf4[threadIdx.x + 128];
  }

  const int t = threadIdx.x;
  const int base = blockIdx.x * 512 + t;
  bool act[4];
  float4 xa[4], xb[4];
  #pragma unroll
  for (int g = 0; g < 4; ++g) {
    int gid = base + g * 128;
    act[g] = gid < N;
    const float4* Xv =
        reinterpret_cast<const float4*>(X) + (size_t)(act[g] ? gid : 0) * 2;
    xa[g] = Xv[0];
    xb[g] = Xv[1];
  }
  __syncthreads();                            // staging complete

  // two f2 packs: lanes {pt0,pt1} and {pt2,pt3}
  f2 xs01[8], xs23[8];
  xs01[0] = (f2){xa[0].x, xa[1].x}; xs23[0] = (f2){xa[2].x, xa[3].x};
  xs01[1] = (f2){xa[0].y, xa[1].y}; xs23[1] = (f2){xa[2].y, xa[3].y};
  xs01[2] = (f2){xa[0].z, xa[1].z}; xs23[2] = (f2){xa[2].z, xa[3].z};
  xs01[3] = (f2){xa[0].w, xa[1].w}; xs23[3] = (f2){xa[2].w, xa[3].w};
  xs01[4] = (f2){xb[0].x, xb[1].x}; xs23[4] = (f2){xb[2].x, xb[3].x};
  xs01[5] = (f2){xb[0].y, xb[1].y}; xs23[5] = (f2){xb[2].y, xb[3].y};
  xs01[6] = (f2){xb[0].z, xb[1].z}; xs23[6] = (f2){xb[2].z, xb[3].z};
  xs01[7] = (f2){xb[0].w, xb[1].w}; xs23[7] = (f2){xb[2].w, xb[3].w};

  constexpr int D_OF[44] = {0,0,0,0,0,0,0,0,0,
                            1,1,1,1,1,1,1,1,
                            2,2,2,2,2,2,2,
                            3,3,3,3,3,3,
                            4,4,4,4,4,
                            5,5,5,5,
                            6,6,6,
                            7,7};
  constexpr int E_OF[44] = {-1,0,1,2,3,4,5,6,7,
                            -1,1,2,3,4,5,6,7,
                            -1,2,3,4,5,6,7,
                            -1,3,4,5,6,7,
                            -1,4,5,6,7,
                            -1,5,6,7,
                            -1,6,7,
                            -1,7};

  f2 u01[16], u23[16];
  #pragma unroll
  for (int i = 0; i < 16; ++i) {
    const float4* c4 = reinterpret_cast<const float4*>(sc + i * 48);
    f2 g01 = (f2){0.f, 0.f}, g23 = (f2){0.f, 0.f};
    f2 r01 = (f2){0.f, 0.f}, r23 = (f2){0.f, 0.f};
    #pragma unroll
    for (int v = 0; v < 11; ++v) {            // 11x ds_read_b128 broadcast
      float4 w = c4[v];
      #pragma unroll
      for (int k2 = 0; k2 < 4; ++k2) {
        const int q = 4 * v + k2;
        const float cc = (k2 == 0) ? w.x : (k2 == 1) ? w.y : (k2 == 2) ? w.z : w.w;
        if (E_OF[q] < 0) {                    // start of row d: flush prev row
          if (q > 0) {
            g01 = __builtin_elementwise_fma(xs01[D_OF[q - 1]], r01, g01);
            g23 = __builtin_elementwise_fma(xs23[D_OF[q - 1]], r23, g23);
          }
          r01 = (f2){cc, cc};
          r23 = (f2){cc, cc};
        } else {
          r01 = vfma(cc, xs01[E_OF[q]], r01);
          r23 = vfma(cc, xs23[E_OF[q]], r23);
        }
      }
    }
    g01 = __builtin_elementwise_fma(xs01[7], r01, g01);  // flush row 7
    g23 = __builtin_elementwise_fma(xs23[7], r23, g23);
    u01[i] = (f2){fexp2(g01.x), fexp2(g01.y)};
    u23[i] = (f2){fexp2(g23.x), fexp2(g23.y)};
  }

  constexpr int EOFF[16]  = {0,4,8,12,16,24,32,40,48,60,72,84,96,112,128,144};
  constexpr int ELEN4[16] = {1,1,1,1,2,2,2,2,3,3,3,3,4,4,4,4};
  const float4* es4 = reinterpret_cast<const float4*>(sc + 768);
  f2 pdf01 = (f2){0.f, 0.f}, pdf23 = (f2){0.f, 0.f};
  #pragma unroll
  for (int i = 0; i < 16; ++i) {
    f2 s01 = (f2){0.f, 0.f}, s23 = (f2){0.f, 0.f};
    #pragma unroll
    for (int q4 = 0; q4 < ELEN4[i]; ++q4) {   // ds_read_b128 per 4 E entries
      float4 ev = es4[EOFF[i] / 4 + q4];
      const int j = q4 * 4;
      s01 = vfma(ev.x, u01[j + 0], s01); s23 = vfma(ev.x, u23[j + 0], s23);
      s01 = vfma(ev.y, u01[j + 1], s01); s23 = vfma(ev.y, u23[j + 1], s23);
      s01 = vfma(ev.z, u01[j + 2], s01); s23 = vfma(ev.z, u23[j + 2], s23);
      s01 = vfma(ev.w, u01[j + 3], s01); s23 = vfma(ev.w, u23[j + 3], s23);
    }
    pdf01 = __builtin_elementwise_fma(u01[i], s01, pdf01);
    pdf23 = __builtin_elementwise_fma(u23[i], s23, pdf23);
  }
  float lsum = 0.f;
  if (act[0]) lsum += flog2(pdf01.x);
  if (act[1]) lsum += flog2(pdf01.y);
  if (act[2]) lsum += flog2(pdf23.x);
  if (act[3]) lsum += flog2(pdf23.y);

  // deterministic block reduction (2 waves)
  #pragma unroll
  for (int off = 32; off > 0; off >>= 1) lsum += __shfl_down(lsum, off, 64);
  __shared__ float wsum[2];
  int lane = threadIdx.x & 63, wid = threadIdx.x >> 6;
  if (lane == 0) wsum[wid] = lsum;
  __syncthreads();
  if (threadIdx.x == 0)
    partials[blockIdx.x] = wsum[0] + wsum[1];
}

// ---------------------------------------------------------------------------
// Kernel C: deterministic final reduction (fixed-order strided + tree)
// ---------------------------------------------------------------------------
__global__ __launch_bounds__(256) void gm_final(const float* __restrict__ ws,
                                                float* __restrict__ out,
                                                int nb, float invN) {
  const float* partials = ws + WS_PART;
  float s = 0.f;
  for (int t = threadIdx.x; t < nb; t += 256) s += partials[t];
  #pragma unroll
  for (int off = 32; off > 0; off >>= 1) s += __shfl_down(s, off, 64);
  __shared__ float wsum[4];
  int lane = threadIdx.x & 63, wid = threadIdx.x >> 6;
  if (lane == 0) wsum[wid] = s;
  __syncthreads();
  if (threadIdx.x == 0) {
    float tot = (wsum[0] + wsum[1]) + (wsum[2] + wsum[3]);
    // mean(ln pdf_true) + ln z_last = ln2 * mean(log2 pdf_scaled) + Kconst
    out[0] = tot * LN2_F * invN + ws[WS_K];
  }
}

extern "C" void kernel_launch(void* const* d_in, const int* in_sizes, int n_in,
                              void* d_out, int out_size, void* d_ws, size_t ws_size,
                              hipStream_t stream) {
  const float* X = (const float*)d_in[0];
  const float* mu = (const float*)d_in[1];
  const float* L = (const float*)d_in[2];
  const float* wts = (const float*)d_in[3];
  // d_in[4] ("it") is unused by the reference math.
  float* ws = (float*)d_ws;
  float* out = (float*)d_out;
  int N = in_sizes[0] / 8;
  int nb = (N + 511) / 512;              // 128 threads x 4 points
  gm_setup<<<1, 256, 0, stream>>>(mu, L, wts, ws);
  gm_main<<<nb, 128, 0, stream>>>(X, ws, ws + WS_PART, N);
  gm_final<<<1, 256, 0, stream>>>(ws, out, nb, 1.0f / (float)N);
}

// Round 15
// 24.487 us; speedup vs baseline: 5.3659x; 1.0178x over previous
//
#include <hip/hip_runtime.h>
#include <math.h>

// ---------------------------------------------------------------------------
// N-pair Gaussian mixture log-likelihood, factorized form:
//   arg_ij(x) = g_i(x) + g_j(x) + c_ij,  g_i(x) = -0.5 x'prec_i x + x'rhs_i
//   pdf(x)    = u' E u,  u_i = exp(g_i(x)),  E_ij = exp(c_ij + 64 ln2)  [scaled]
//   out       = mean_n( log pdf_n ) + log z_last   (scale folded into Kconst)
// Measured-optimal configuration (session round 7, 24.03 us):
// three dispatches; main = 256 threads, 4 pts/thread, constants staged to LDS
// once per block and read as float4 broadcasts (ds_read_b128, conflict-free).
// No atomics, no fences -> deterministic.
// ---------------------------------------------------------------------------

#define LOG2E_F 1.4426950408889634f
#define LN2_F   0.6931471805599453f
#define LN2PI_F 1.8378770664093453f   // ln(2*pi)

// ws layout (float offsets). Staged region = [0,1024) = 256 float4.
#define WS_COEF 0      // 16 rows * 48: per d {lin_d, Q_dd..Q_d7} *log2e; 44 used
#define WS_ES   768    // 160: packed lower-tri E rows, each padded to 16B
#define WS_K    1024   // Kconst = log z_last - 64 ln2  (outside staged region)
#define WS_PART 1088   // per-block partial sums

// Padded-packed E row offsets (floats) and lengths (float4)
__device__ const int EOFF_D[16]  = {0,4,8,12,16,24,32,40,48,60,72,84,96,112,128,144};

__device__ __forceinline__ float fexp2(float x) {
#if __has_builtin(__builtin_amdgcn_exp2f)
  return __builtin_amdgcn_exp2f(x);
#else
  return exp2f(x);
#endif
}
__device__ __forceinline__ float flog2(float x) {
#if __has_builtin(__builtin_amdgcn_logf)
  return __builtin_amdgcn_logf(x);
#else
  return log2f(x);
#endif
}

// Cholesky: A = C C^T (lower). Only lower triangle of A read. Fully unrolled.
__device__ __forceinline__ void chol8(const float (*A)[8], float (*C)[8]) {
  #pragma unroll
  for (int d = 0; d < 8; ++d) {
    float s = A[d][d];
    #pragma unroll
    for (int m = 0; m < 8; ++m) if (m < d) s -= C[d][m] * C[d][m];
    float cd = sqrtf(s);
    C[d][d] = cd;
    float inv = 1.f / cd;
    #pragma unroll
    for (int e = 0; e < 8; ++e) if (e > d) {
      float t = A[e][d];
      #pragma unroll
      for (int m = 0; m < 8; ++m) if (m < d) t -= C[e][m] * C[d][m];
      C[e][d] = t * inv;
    }
  }
}

// ---------------------------------------------------------------------------
// Kernel A: all setup in one block.
// ---------------------------------------------------------------------------
__global__ __launch_bounds__(256) void gm_setup(const float* __restrict__ mu,
                                                const float* __restrict__ L,
                                                const float* __restrict__ wts,
                                                float* __restrict__ ws) {
  __shared__ float sp[16][72];   // prec[64] + rhs[8] per component
  int tid = threadIdx.x;
  ws[768 + tid] = 0.f;           // zero [768,1024): E pads + tail
  if (tid < 16) {
    int k = tid;
    float Lt[8][8];
    #pragma unroll
    for (int d = 0; d < 8; ++d)
      #pragma unroll
      for (int e = 0; e < 8; ++e)
        Lt[d][e] = (e <= d) ? L[k * 64 + d * 8 + e] : 0.f;
    float A[8][8];
    #pragma unroll
    for (int d = 0; d < 8; ++d)
      #pragma unroll
      for (int e = 0; e <= d; ++e) {
        float s = (d == e) ? 1.f : 0.f;
        #pragma unroll
        for (int m = 0; m < 8; ++m) s += Lt[d][m] * Lt[e][m];
        A[d][e] = s;
        A[e][d] = s;
      }
    float C[8][8];
    chol8(A, C);
    float Ci[8][8];
    #pragma unroll
    for (int d = 0; d < 8; ++d) Ci[d][d] = 1.f / C[d][d];
    #pragma unroll
    for (int e = 0; e < 8; ++e)
      #pragma unroll
      for (int d = 0; d < 8; ++d) if (d > e) {
        float s = 0.f;
        #pragma unroll
        for (int m = 0; m < 8; ++m) if (m >= e && m < d) s += C[d][m] * Ci[m][e];
        Ci[d][e] = -s * Ci[d][d];
      }
    #pragma unroll
    for (int a = 0; a < 8; ++a)
      #pragma unroll
      for (int b = 0; b < 8; ++b) {
        float s = 0.f;
        #pragma unroll
        for (int m = 0; m < 8; ++m) if (m >= a && m >= b) s += Ci[m][a] * Ci[m][b];
        sp[k][a * 8 + b] = s;
      }
    #pragma unroll
    for (int d = 0; d < 8; ++d) {
      float s = 0.f;
      #pragma unroll
      for (int e = 0; e < 8; ++e) s += sp[k][d * 8 + e] * mu[k * 8 + e];
      sp[k][64 + d] = s;
    }
  }
  __syncthreads();   // sp ready; zeroing of [768,1024) visible block-wide

  int p = tid;
  int i = p >> 4, j = p & 15;
  const float* pi = sp[i];
  const float* pj = sp[j];
  float P[8][8], rp[8];
  #pragma unroll
  for (int d = 0; d < 8; ++d) {
    #pragma unroll
    for (int e = 0; e < 8; ++e) P[d][e] = pi[d * 8 + e] + pj[d * 8 + e];
    rp[d] = pi[64 + d] + pj[64 + d];
  }
  float U[8][8];
  chol8(P, U);
  float logdet = 0.f;
  #pragma unroll
  for (int d = 0; d < 8; ++d) logdet += logf(U[d][d]);
  logdet *= 2.f;
  float zf[8];
  #pragma unroll
  for (int d = 0; d < 8; ++d) {
    float s = rp[d];
    #pragma unroll
    for (int m = 0; m < 8; ++m) if (m < d) s -= U[d][m] * zf[m];
    zf[d] = s / U[d][d];
  }
  float y[8];
  #pragma unroll
  for (int dd = 7; dd >= 0; --dd) {
    float s = zf[dd];
    #pragma unroll
    for (int m = 0; m < 8; ++m) if (m > dd) s -= U[m][dd] * y[m];
    y[dd] = s / U[dd][dd];
  }
  float muPmu = 0.f;
  #pragma unroll
  for (int d = 0; d < 8; ++d) muPmu += rp[d] * y[d];
  // c'_ij = -0.5 mu'Pmu + 0.5 log det P - 32 ln(2pi) + ln w_i + ln w_j + 64 ln2
  float c = -0.5f * muPmu + 0.5f * logdet - 32.f * LN2PI_F
          + logf(wts[i]) + logf(wts[j]) + 64.f * LN2_F;
  float Ev = expf(c);
  if (j <= i)   // padded-packed lower triangle; factor 2 folded off-diagonal
    ws[WS_ES + EOFF_D[i] + j] = (i == j) ? Ev : 2.f * Ev;
  if (i == j) { // main-loop coefficient row, interleaved {lin_d, Q_dd..Q_d7}
    float* c0 = ws + WS_COEF + i * 48;
    int q = 0;
    #pragma unroll
    for (int d = 0; d < 8; ++d) {
      c0[q++] = pi[64 + d] * LOG2E_F;                 // lin_d
      #pragma unroll
      for (int e = d; e < 8; ++e) {
        float v = (d == e) ? -0.5f * pi[d * 8 + e] : -pi[d * 8 + e];
        c0[q++] = v * LOG2E_F;                        // Q_de
      }
    }
    c0[44] = 0.f; c0[45] = 0.f; c0[46] = 0.f; c0[47] = 0.f;
  }
  if (p == 255) ws[WS_K] = 0.5f * logdet - 32.f * LN2PI_F - 64.f * LN2_F;
}

// ---------------------------------------------------------------------------
// Kernel B: main N-loop, 4 points per thread. 1024-float constant table is
// staged into LDS (one float4 per thread) and read back exclusively as
// float4 (ds_read_b128 broadcasts): 176 coef + 40 E reads per point-set.
// ---------------------------------------------------------------------------
__global__ __launch_bounds__(256) void gm_main(const float* __restrict__ X,
                                               const float* __restrict__ cf,
                                               float* __restrict__ partials,
                                               int N) {
  __shared__ float sc[1024];   // [0,768) coef rows; [768,928) padded E; pad
  {
    const float4* cf4 = reinterpret_cast<const float4*>(cf);
    reinterpret_cast<float4*>(sc)[threadIdx.x] = cf4[threadIdx.x];
  }

  const int t = threadIdx.x;
  const int base = blockIdx.x * 1024 + t;
  float xs[4][8];
  bool act[4];
  #pragma unroll
  for (int g = 0; g < 4; ++g) {
    int gid = base + g * 256;
    act[g] = gid < N;
    int src = act[g] ? gid : 0;            // clamp: X[0..7] is valid memory
    const float4* Xv = reinterpret_cast<const float4*>(X) + (size_t)src * 2;
    float4 a = Xv[0], b = Xv[1];
    xs[g][0] = a.x; xs[g][1] = a.y; xs[g][2] = a.z; xs[g][3] = a.w;
    xs[g][4] = b.x; xs[g][5] = b.y; xs[g][6] = b.z; xs[g][7] = b.w;
  }
  __syncthreads();                          // staging complete

  // u[g][i] = exp(g_i(x_g)) with log2e pre-folded into coefficients
  float u[4][16];
  #pragma unroll
  for (int i = 0; i < 16; ++i) {
    const float4* c4 = reinterpret_cast<const float4*>(sc + i * 48);
    float cr[44];
    #pragma unroll
    for (int v = 0; v < 11; ++v) {          // 11x ds_read_b128
      float4 w = c4[v];
      cr[4 * v + 0] = w.x; cr[4 * v + 1] = w.y;
      cr[4 * v + 2] = w.z; cr[4 * v + 3] = w.w;
    }
    float g0 = 0.f, g1 = 0.f, g2 = 0.f, g3 = 0.f;
    int q = 0;
    #pragma unroll
    for (int d = 0; d < 8; ++d) {
      float lc = cr[q++];
      float r0 = lc, r1 = lc, r2 = lc, r3 = lc;   // lin_d
      #pragma unroll
      for (int e = d; e < 8; ++e) {
        float cc = cr[q++];
        r0 = fmaf(cc, xs[0][e], r0);
        r1 = fmaf(cc, xs[1][e], r1);
        r2 = fmaf(cc, xs[2][e], r2);
        r3 = fmaf(cc, xs[3][e], r3);
      }
      g0 = fmaf(xs[0][d], r0, g0);
      g1 = fmaf(xs[1][d], r1, g1);
      g2 = fmaf(xs[2][d], r2, g2);
      g3 = fmaf(xs[3][d], r3, g3);
    }
    u[0][i] = fexp2(g0);
    u[1][i] = fexp2(g1);
    u[2][i] = fexp2(g2);
    u[3][i] = fexp2(g3);
  }

  // pdf = sum_i u_i * (padded row_i . u)   [diag=E'_ii, off=2E'_ij, pads=0]
  constexpr int EOFF[16]  = {0,4,8,12,16,24,32,40,48,60,72,84,96,112,128,144};
  constexpr int ELEN4[16] = {1,1,1,1,2,2,2,2,3,3,3,3,4,4,4,4};
  const float4* es4 = reinterpret_cast<const float4*>(sc + 768);
  float p0 = 0.f, p1 = 0.f, p2 = 0.f, p3 = 0.f;
  #pragma unroll
  for (int i = 0; i < 16; ++i) {
    float s0 = 0.f, s1 = 0.f, s2 = 0.f, s3 = 0.f;
    #pragma unroll
    for (int q4 = 0; q4 < ELEN4[i]; ++q4) {  // ds_read_b128 per 4 E entries
      float4 ev = es4[EOFF[i] / 4 + q4];
      const int j = q4 * 4;
      s0 = fmaf(ev.x, u[0][j + 0], s0); s0 = fmaf(ev.y, u[0][j + 1], s0);
      s0 = fmaf(ev.z, u[0][j + 2], s0); s0 = fmaf(ev.w, u[0][j + 3], s0);
      s1 = fmaf(ev.x, u[1][j + 0], s1); s1 = fmaf(ev.y, u[1][j + 1], s1);
      s1 = fmaf(ev.z, u[1][j + 2], s1); s1 = fmaf(ev.w, u[1][j + 3], s1);
      s2 = fmaf(ev.x, u[2][j + 0], s2); s2 = fmaf(ev.y, u[2][j + 1], s2);
      s2 = fmaf(ev.z, u[2][j + 2], s2); s2 = fmaf(ev.w, u[2][j + 3], s2);
      s3 = fmaf(ev.x, u[3][j + 0], s3); s3 = fmaf(ev.y, u[3][j + 1], s3);
      s3 = fmaf(ev.z, u[3][j + 2], s3); s3 = fmaf(ev.w, u[3][j + 3], s3);
    }
    p0 = fmaf(u[0][i], s0, p0);
    p1 = fmaf(u[1][i], s1, p1);
    p2 = fmaf(u[2][i], s2, p2);
    p3 = fmaf(u[3][i], s3, p3);
  }
  float lsum = 0.f;
  if (act[0]) lsum += flog2(p0);
  if (act[1]) lsum += flog2(p1);
  if (act[2]) lsum += flog2(p2);
  if (act[3]) lsum += flog2(p3);

  // deterministic block reduction of sum(log2 pdf)
  #pragma unroll
  for (int off = 32; off > 0; off >>= 1) lsum += __shfl_down(lsum, off, 64);
  __shared__ float wsum[4];
  int lane = threadIdx.x & 63, wid = threadIdx.x >> 6;
  if (lane == 0) wsum[wid] = lsum;
  __syncthreads();
  if (threadIdx.x == 0)
    partials[blockIdx.x] = (wsum[0] + wsum[1]) + (wsum[2] + wsum[3]);
}

// ---------------------------------------------------------------------------
// Kernel C: deterministic final reduction (fixed-order strided + tree)
// ---------------------------------------------------------------------------
__global__ __launch_bounds__(256) void gm_final(const float* __restrict__ ws,
                                                float* __restrict__ out,
                                                int nb, float invN) {
  const float* partials = ws + WS_PART;
  float s = 0.f;
  for (int t = threadIdx.x; t < nb; t += 256) s += partials[t];
  #pragma unroll
  for (int off = 32; off > 0; off >>= 1) s += __shfl_down(s, off, 64);
  __shared__ float wsum[4];
  int lane = threadIdx.x & 63, wid = threadIdx.x >> 6;
  if (lane == 0) wsum[wid] = s;
  __syncthreads();
  if (threadIdx.x == 0) {
    float tot = (wsum[0] + wsum[1]) + (wsum[2] + wsum[3]);
    // mean(ln pdf_true) + ln z_last = ln2 * mean(log2 pdf_scaled) + Kconst
    out[0] = tot * LN2_F * invN + ws[WS_K];
  }
}

extern "C" void kernel_launch(void* const* d_in, const int* in_sizes, int n_in,
                              void* d_out, int out_size, void* d_ws, size_t ws_size,
                              hipStream_t stream) {
  const float* X = (const float*)d_in[0];
  const float* mu = (const float*)d_in[1];
  const float* L = (const float*)d_in[2];
  const float* wts = (const float*)d_in[3];
  // d_in[4] ("it") is unused by the reference math.
  float* ws = (float*)d_ws;
  float* out = (float*)d_out;
  int N = in_sizes[0] / 8;
  int nb = (N + 1023) / 1024;            // 4 points per thread, 256 threads
  gm_setup<<<1, 256, 0, stream>>>(mu, L, wts, ws);
  gm_main<<<nb, 256, 0, stream>>>(X, ws, ws + WS_PART, N);
  gm_final<<<1, 256, 0, stream>>>(ws, out, nb, 1.0f / (float)N);
}